// Round 14
// baseline (523.751 us; speedup 1.0000x reference)
//
#include <hip/hip_runtime.h>
#include <hip/hip_bf16.h>
#include <hip/hip_cooperative_groups.h>
#include <math.h>

namespace cg = cooperative_groups;

// Problem constants (from reference)
constexpr int kN2 = 180224, kN1 = 11264, kN0 = 1024;
constexpr int kE1 = 168960, kE2 = 10240;
constexpr int kIN = 602, kHID = 256, kOUT = 41;
constexpr int kKP = 608;  // kIN padded to multiple of 32 (MFMA K)

typedef __attribute__((ext_vector_type(8))) short bf16x8;
typedef __attribute__((ext_vector_type(4))) float f32x4;

static __device__ __forceinline__ ushort f2bf(float v) {
    return __bfloat16_as_ushort(__float2bfloat16(v));
}
static __device__ __forceinline__ uint pack2(float a, float b) {
    return (uint)f2bf(a) | ((uint)f2bf(b) << 16);
}

// ---------------------------------------------------------------------------
// Cooperative prep: zero -> hist -> (scan || W1-convert || W2-transpose)
// -> bucket, with grid.sync() between phases. Replaces 4 graph nodes.
// Grid 1024 x 256 (4 blocks/CU, low VGPR -> co-residency guaranteed).
// ---------------------------------------------------------------------------
__global__ __launch_bounds__(256)
void coop_prep(const int* __restrict__ dst1, const int* __restrict__ dst2,
               const int* __restrict__ src1, const int* __restrict__ src2,
               int* __restrict__ cnt1, int* __restrict__ cnt2,
               int* __restrict__ cur1, int* __restrict__ cur2,
               int* __restrict__ off1, int* __restrict__ off2,
               int* __restrict__ ebuf1, int* __restrict__ ebuf2,
               const float* __restrict__ W1l, const float* __restrict__ W1r,
               ushort* __restrict__ wlt, ushort* __restrict__ wrt,
               const float* __restrict__ W2l, const float* __restrict__ W2r,
               float* __restrict__ w2lt, float* __restrict__ w2rt) {
    cg::grid_group grid = cg::this_grid();
    const int t = threadIdx.x;
    const int gid = blockIdx.x * 256 + t;

    // phase 0: zero cnt1/cur1/cnt2/cur2 (contiguous from cnt1)
    if (gid < 2 * kN1 + 2 * kN0) cnt1[gid] = 0;
    grid.sync();

    // phase 1: histogram
    if (gid < kE1) {
        atomicAdd(&cnt1[dst1[gid]], 1);
    } else if (gid < kE1 + kE2) {
        atomicAdd(&cnt2[dst2[gid - kE1]], 1);
    }
    grid.sync();

    // phase 2: blocks 0,1 scan; 2..513 W1 convert; 514,515 W2 transpose
    if (blockIdx.x < 2) {
        __shared__ int part[256];
        const int* cnt = blockIdx.x ? cnt2 : cnt1;
        int* off = blockIdx.x ? off2 : off1;
        const int nN = blockIdx.x ? kN0 : kN1;
        const int CH = nN >> 8;
        const int base = t * CH;
        int s = 0;
        for (int i = 0; i < CH; ++i) s += cnt[base + i];
        part[t] = s;
        __syncthreads();
        for (int ofs = 1; ofs < 256; ofs <<= 1) {
            int v = (t >= ofs) ? part[t - ofs] : 0;
            __syncthreads();
            if (t >= ofs) part[t] += v;
            __syncthreads();
        }
        int run = (t == 0) ? 0 : part[t - 1];
        for (int i = 0; i < CH; ++i) {
            off[base + i] = run;
            run += cnt[base + i];
        }
        if (t == 255) off[nN] = run;
    } else if (blockIdx.x < 514) {
        const int idx = blockIdx.x - 2;
        const int which = idx >> 8;
        const int j = idx & 255;
        const float* W = which ? W1r : W1l;
        ushort* Wt = which ? wrt : wlt;
        for (int k = t; k < kKP; k += 256) {
            float v = (k < kIN) ? W[(size_t)k * kHID + j] : 0.f;
            Wt[(size_t)j * kKP + k] = f2bf(v);
        }
    } else if (blockIdx.x < 516) {
        const int which = blockIdx.x - 514;
        const float* W = which ? W2r : W2l;
        float* Wt = which ? w2rt : w2lt;
        for (int idx = t; idx < kOUT * kHID; idx += 256) {
            const int tr = idx >> 8;
            const int k = idx & 255;
            Wt[idx] = W[(size_t)k * kOUT + tr];
        }
    }
    grid.sync();

    // phase 3: bucket scatter
    if (gid < kE1) {
        const int d = dst1[gid];
        const int p = atomicAdd(&cur1[d], 1);
        ebuf1[off1[d] + p] = src1[gid];
    } else if (gid < kE1 + kE2) {
        const int e = gid - kE1;
        const int d = dst2[e];
        const int p = atomicAdd(&cur2[d], 1);
        ebuf2[off2[d] + p] = src2[e];
    }
}

// ---------------------------------------------------------------------------
// Aggregation layer 1 + x[:N1] conversion fused (unchanged from R13;
// measured at its delivered-bytes roofline ~6.2 TB/s).
// ---------------------------------------------------------------------------
__global__ __launch_bounds__(128)
void aggregate1_kernel(const float* __restrict__ x, const int* __restrict__ off,
                       const int* __restrict__ ebuf, ushort* __restrict__ aggb,
                       ushort* __restrict__ xb) {
    const int d = blockIdx.x;
    const int t = threadIdx.x;
    const int b = off[d], e = off[d + 1];
    float p0x = 0.f, p0y = 0.f, p1x = 0.f, p1y = 0.f, p2x = 0.f, p2y = 0.f;
    float q0x = 0.f, q0y = 0.f, q1x = 0.f, q1y = 0.f, q2x = 0.f, q2y = 0.f;
    int i = b;
    for (; i + 4 <= e; i += 4) {
        const int s0 = ebuf[i], s1 = ebuf[i + 1];
        const int s2 = ebuf[i + 2], s3 = ebuf[i + 3];
        const float2* r0 = (const float2*)(x + (size_t)s0 * kIN);
        const float2* r1 = (const float2*)(x + (size_t)s1 * kIN);
        const float2* r2 = (const float2*)(x + (size_t)s2 * kIN);
        const float2* r3 = (const float2*)(x + (size_t)s3 * kIN);
        const float2 a0 = r0[t], a1 = r0[t + 128];
        const float2 b0 = r1[t], b1 = r1[t + 128];
        const float2 c0 = r2[t], c1 = r2[t + 128];
        const float2 d0 = r3[t], d1 = r3[t + 128];
        p0x += a0.x; p0y += a0.y; p1x += a1.x; p1y += a1.y;
        q0x += b0.x; q0y += b0.y; q1x += b1.x; q1y += b1.y;
        p0x += c0.x; p0y += c0.y; p1x += c1.x; p1y += c1.y;
        q0x += d0.x; q0y += d0.y; q1x += d1.x; q1y += d1.y;
        if (t < 45) {
            const float2 a2 = r0[t + 256], b2 = r1[t + 256];
            const float2 c2 = r2[t + 256], d2 = r3[t + 256];
            p2x += a2.x + c2.x; p2y += a2.y + c2.y;
            q2x += b2.x + d2.x; q2y += b2.y + d2.y;
        }
    }
    for (; i < e; ++i) {
        const int s0 = ebuf[i];
        const float2* r0 = (const float2*)(x + (size_t)s0 * kIN);
        const float2 a0 = r0[t], a1 = r0[t + 128];
        p0x += a0.x; p0y += a0.y; p1x += a1.x; p1y += a1.y;
        if (t < 45) {
            const float2 a2 = r0[t + 256];
            p2x += a2.x; p2y += a2.y;
        }
    }
    p0x += q0x; p0y += q0y; p1x += q1x; p1y += q1y; p2x += q2x; p2y += q2y;
    const float inv = 1.0f / fmaxf((float)(e - b), 1.0f);
    uint* ar = (uint*)(aggb + (size_t)d * kKP);
    ar[t]       = pack2(p0x * inv, p0y * inv);
    ar[t + 128] = pack2(p1x * inv, p1y * inv);
    if (t < 45) ar[t + 256] = pack2(p2x * inv, p2y * inv);
    if (t >= 45 && t < 48) ar[t + 256] = 0u;

    const float2* xr = (const float2*)(x + (size_t)d * kIN);
    uint* xo = (uint*)(xb + (size_t)d * kKP);
#pragma unroll
    for (int u = t; u < 304; u += 128) {
        uint v = 0u;
        if (u < 301) {
            const float2 f = xr[u];
            v = pack2(f.x, f.y);
        }
        xo[u] = v;
    }
}

// ---------------------------------------------------------------------------
// Cooperative layer1+layer2: 256 blocks x 512 threads (1 block/CU, fits
// cooperative co-residency even at ~150 VGPR).
// Phase A: barrier-free depth-3 MFMA GEMM, grid-stride over 352 64x128
//   tiles (same body/swizzle as R13).
// grid.sync()
// Phase B: layer2, one wave per dst node (wave-local LDS slice, no block
//   barrier): gather-mean h rows + float4 GEMV (transposed W2) + log_softmax.
// ---------------------------------------------------------------------------
struct L1Frags {
    bf16x8 a[2];
    bf16x8 xx[2];
    bf16x8 wl[2];
    bf16x8 wr[2];
};

__global__ __launch_bounds__(512)
void l1l2_coop(const ushort* __restrict__ aggb, const ushort* __restrict__ xb,
               const ushort* __restrict__ wlt, const ushort* __restrict__ wrt,
               const float* __restrict__ b1, float* __restrict__ h,
               const int* __restrict__ off2, const int* __restrict__ ebuf2,
               const float* __restrict__ w2lt, const float* __restrict__ w2rt,
               const float* __restrict__ b2, float* __restrict__ out) {
    cg::grid_group gg = cg::this_grid();
    __shared__ float s2[8][2][kHID];  // per-wave sa/sh slices (16KB)
    const int t = threadIdx.x;
    const int lane = t & 63, wid = t >> 6;
    const int wr_ = wid >> 2, wc = wid & 3;
    const int rl = lane & 15;
    const int k8 = lane >> 4;
    const int col_l = lane & 15, rq = lane >> 4;

    // ---------------- Phase A: layer-1 GEMM over 352 tiles ----------------
    for (int tt = blockIdx.x; tt < 352; tt += 256) {
        const int bid = (tt & 7) * 44 + (tt >> 3);  // bijective XCD swizzle
        const int mt = bid >> 1, nt = bid & 1;
        const int mrow = mt * 64 + wr_ * 32;
        const int jbase = nt * 128 + wc * 32;

        const ushort* pa0 = aggb + (size_t)(mrow + rl) * kKP + k8 * 8;
        const ushort* pa1 = pa0 + 16 * kKP;
        const ushort* px0 = xb + (size_t)(mrow + rl) * kKP + k8 * 8;
        const ushort* px1 = px0 + 16 * kKP;
        const ushort* pl0 = wlt + (size_t)(jbase + rl) * kKP + k8 * 8;
        const ushort* pl1 = pl0 + 16 * kKP;
        const ushort* pr0 = wrt + (size_t)(jbase + rl) * kKP + k8 * 8;
        const ushort* pr1 = pr0 + 16 * kKP;

        const float bias0 = b1[jbase + col_l];
        const float bias1 = b1[jbase + 16 + col_l];

        f32x4 acc[2][2];
#pragma unroll
        for (int m = 0; m < 2; ++m)
#pragma unroll
            for (int n = 0; n < 2; ++n) acc[m][n] = (f32x4){0.f, 0.f, 0.f, 0.f};

#define L1_LOAD(F, ks)                                               \
    do {                                                             \
        const int o = (ks) * 32;                                     \
        (F).a[0]  = *(const bf16x8*)(pa0 + o);                       \
        (F).a[1]  = *(const bf16x8*)(pa1 + o);                       \
        (F).xx[0] = *(const bf16x8*)(px0 + o);                       \
        (F).xx[1] = *(const bf16x8*)(px1 + o);                       \
        (F).wl[0] = *(const bf16x8*)(pl0 + o);                       \
        (F).wl[1] = *(const bf16x8*)(pl1 + o);                       \
        (F).wr[0] = *(const bf16x8*)(pr0 + o);                       \
        (F).wr[1] = *(const bf16x8*)(pr1 + o);                       \
    } while (0)

#define L1_MFMA(F)                                                   \
    do {                                                             \
        _Pragma("unroll") for (int m = 0; m < 2; ++m)                \
            _Pragma("unroll") for (int n = 0; n < 2; ++n) {          \
            acc[m][n] = __builtin_amdgcn_mfma_f32_16x16x32_bf16(     \
                (F).a[m], (F).wl[n], acc[m][n], 0, 0, 0);            \
            acc[m][n] = __builtin_amdgcn_mfma_f32_16x16x32_bf16(     \
                (F).xx[m], (F).wr[n], acc[m][n], 0, 0, 0);           \
        }                                                            \
    } while (0)

        L1Frags fr0, fr1, fr2;
        L1_LOAD(fr0, 0);
        L1_LOAD(fr1, 1);
        L1_LOAD(fr2, 2);
        L1_MFMA(fr0); L1_LOAD(fr0, 3);
        L1_MFMA(fr1); L1_LOAD(fr1, 4);
        L1_MFMA(fr2); L1_LOAD(fr2, 5);
        L1_MFMA(fr0); L1_LOAD(fr0, 6);
        L1_MFMA(fr1); L1_LOAD(fr1, 7);
        L1_MFMA(fr2); L1_LOAD(fr2, 8);
        L1_MFMA(fr0); L1_LOAD(fr0, 9);
        L1_MFMA(fr1); L1_LOAD(fr1, 10);
        L1_MFMA(fr2); L1_LOAD(fr2, 11);
        L1_MFMA(fr0); L1_LOAD(fr0, 12);
        L1_MFMA(fr1); L1_LOAD(fr1, 13);
        L1_MFMA(fr2); L1_LOAD(fr2, 14);
        L1_MFMA(fr0); L1_LOAD(fr0, 15);
        L1_MFMA(fr1); L1_LOAD(fr1, 16);
        L1_MFMA(fr2); L1_LOAD(fr2, 17);
        L1_MFMA(fr0); L1_LOAD(fr0, 18);
        L1_MFMA(fr1);
        L1_MFMA(fr2);
        L1_MFMA(fr0);
#undef L1_LOAD
#undef L1_MFMA

#pragma unroll
        for (int m = 0; m < 2; ++m)
#pragma unroll
            for (int n = 0; n < 2; ++n) {
                const int gc = jbase + n * 16 + col_l;
                const float bias = n ? bias1 : bias0;
#pragma unroll
                for (int q = 0; q < 4; ++q) {
                    const int gr = mrow + m * 16 + rq * 4 + q;
                    h[(size_t)gr * kHID + gc] = fmaxf(acc[m][n][q] + bias, 0.f);
                }
            }
    }

    gg.sync();

    // ---------------- Phase B: layer 2, one wave per node ----------------
    const int n = wid * 256 + (int)blockIdx.x;  // 0..2047, use first kN0
    if (n < kN0) {
        float* sa = &s2[wid][0][0];
        float* sh = &s2[wid][1][0];
        const int b = off2[n], e = off2[n + 1];
        float ax = 0.f, ay = 0.f, az = 0.f, aw = 0.f;
        for (int i = b; i < e; ++i) {
            const float4 r = ((const float4*)(h + (size_t)ebuf2[i] * kHID))[lane];
            ax += r.x; ay += r.y; az += r.z; aw += r.w;
        }
        const float inv = 1.0f / fmaxf((float)(e - b), 1.0f);
        float4 o;
        o.x = ax * inv; o.y = ay * inv; o.z = az * inv; o.w = aw * inv;
        ((float4*)sa)[lane] = o;
        ((float4*)sh)[lane] = ((const float4*)(h + (size_t)n * kHID))[lane];
        // wave-local LDS RAW: compiler inserts lgkmcnt; no barrier needed.

        float logit = 0.0f;
        if (lane < kOUT) {
            logit = b2[lane];
            const float4* wl4 = (const float4*)(w2lt + (size_t)lane * kHID);
            const float4* wr4 = (const float4*)(w2rt + (size_t)lane * kHID);
            const float4* sa4 = (const float4*)sa;
            const float4* sh4 = (const float4*)sh;
#pragma unroll 8
            for (int k4 = 0; k4 < kHID / 4; ++k4) {
                const float4 a = sa4[k4], hh = sh4[k4];
                const float4 wl = wl4[k4], wr = wr4[k4];
                logit += a.x * wl.x + a.y * wl.y + a.z * wl.z + a.w * wl.w;
                logit += hh.x * wr.x + hh.y * wr.y + hh.z * wr.z + hh.w * wr.w;
            }
        }
        float m = (lane < kOUT) ? logit : -INFINITY;
#pragma unroll
        for (int ofs = 32; ofs >= 1; ofs >>= 1)
            m = fmaxf(m, __shfl_xor(m, ofs));
        float ev = (lane < kOUT) ? expf(logit - m) : 0.0f;
        float s = ev;
#pragma unroll
        for (int ofs = 32; ofs >= 1; ofs >>= 1)
            s += __shfl_xor(s, ofs);
        if (lane < kOUT)
            out[(size_t)n * kOUT + lane] = logit - m - logf(s);
    }
}

// ---------------------------------------------------------------------------
extern "C" void kernel_launch(void* const* d_in, const int* in_sizes, int n_in,
                              void* d_out, int out_size, void* d_ws, size_t ws_size,
                              hipStream_t stream) {
    const float* x    = (const float*)d_in[0];
    const int*   src1 = (const int*)d_in[1];
    const int*   dst1 = (const int*)d_in[2];
    const int*   src2 = (const int*)d_in[3];
    const int*   dst2 = (const int*)d_in[4];
    const float* W1l  = (const float*)d_in[5];
    const float* W1r  = (const float*)d_in[6];
    const float* b1   = (const float*)d_in[7];
    const float* W2l  = (const float*)d_in[8];
    const float* W2r  = (const float*)d_in[9];
    const float* b2   = (const float*)d_in[10];
    float* out = (float*)d_out;

    // ---- workspace layout ----
    int* cnt1 = (int*)d_ws;                  // kN1
    int* cur1 = cnt1 + kN1;                  // kN1
    int* cnt2 = cur1 + kN1;                  // kN0
    int* cur2 = cnt2 + kN0;                  // kN0
    int* off1 = cur2 + kN0;                  // kN1 + 1
    int* off2 = off1 + kN1 + 1;              // kN0 + 1
    int* ebuf1 = off2 + kN0 + 1;             // kE1
    int* ebuf2 = ebuf1 + kE1;                // kE2
    size_t int_words = (size_t)2 * kN1 + 2 * kN0 + (kN1 + 1) + (kN0 + 1) + kE1 + kE2;
    int_words = (int_words + 7) & ~(size_t)7;  // 32B align

    ushort* aggb = (ushort*)((int*)d_ws + int_words);   // kN1*kKP bf16
    ushort* xb   = aggb + (size_t)kN1 * kKP;            // kN1*kKP
    ushort* wlt  = xb + (size_t)kN1 * kKP;              // kHID*kKP
    ushort* wrt  = wlt + (size_t)kHID * kKP;            // kHID*kKP
    float* w2lt  = (float*)(wrt + (size_t)kHID * kKP);  // kOUT*kHID fp32
    float* w2rt  = w2lt + (size_t)kOUT * kHID;          // kOUT*kHID fp32
    float* h     = w2rt + (size_t)kOUT * kHID;          // kN1*kHID fp32

    {
        void* args[] = {(void*)&dst1, (void*)&dst2, (void*)&src1, (void*)&src2,
                        (void*)&cnt1, (void*)&cnt2, (void*)&cur1, (void*)&cur2,
                        (void*)&off1, (void*)&off2, (void*)&ebuf1, (void*)&ebuf2,
                        (void*)&W1l, (void*)&W1r, (void*)&wlt, (void*)&wrt,
                        (void*)&W2l, (void*)&W2r, (void*)&w2lt, (void*)&w2rt};
        hipLaunchCooperativeKernel((void*)coop_prep, dim3(1024), dim3(256),
                                   args, 0, stream);
    }

    aggregate1_kernel<<<kN1, 128, 0, stream>>>(x, off1, ebuf1, aggb, xb);

    {
        void* args[] = {(void*)&aggb, (void*)&xb, (void*)&wlt, (void*)&wrt,
                        (void*)&b1, (void*)&h, (void*)&off2, (void*)&ebuf2,
                        (void*)&w2lt, (void*)&w2rt, (void*)&b2, (void*)&out};
        hipLaunchCooperativeKernel((void*)l1l2_coop, dim3(256), dim3(512),
                                   args, 0, stream);
    }
}

// Round 15
// 195.082 us; speedup vs baseline: 2.6848x; 2.6848x over previous
//
#include <hip/hip_runtime.h>
#include <hip/hip_bf16.h>
#include <math.h>

// Problem constants (from reference)
constexpr int kN2 = 180224, kN1 = 11264, kN0 = 1024;
constexpr int kE1 = 168960, kE2 = 10240;
constexpr int kIN = 602, kHID = 256, kOUT = 41;
constexpr int kKP = 608;  // kIN padded to multiple of 32 (MFMA K)

typedef __attribute__((ext_vector_type(8))) short bf16x8;
typedef __attribute__((ext_vector_type(4))) float f32x4;

static __device__ __forceinline__ ushort f2bf(float v) {
    return __bfloat16_as_ushort(__float2bfloat16(v));
}
static __device__ __forceinline__ uint pack2(float a, float b) {
    return (uint)f2bf(a) | ((uint)f2bf(b) << 16);
}

// ---------------------------------------------------------------------------
// CSR build. hist -> (scan || W1-convert || W2-transpose) -> bucket.
// (R13 structure; cooperative variant measured 300us/sync -- abandoned)
// ---------------------------------------------------------------------------
__global__ __launch_bounds__(256)
void hist_both_kernel(const int* __restrict__ dst1, const int* __restrict__ dst2,
                      int* __restrict__ cnt1, int* __restrict__ cnt2) {
    const int gid = blockIdx.x * 256 + threadIdx.x;
    if (gid < kE1) {
        atomicAdd(&cnt1[dst1[gid]], 1);
    } else if (gid < kE1 + kE2) {
        atomicAdd(&cnt2[dst2[gid - kE1]], 1);
    }
}

// blocks 0,1: scans. blocks 2..513: W1 convert+transpose. 514,515: W2 transpose.
__global__ __launch_bounds__(256)
void scan_convw_kernel(const int* __restrict__ cnt1, int* __restrict__ off1,
                       const int* __restrict__ cnt2, int* __restrict__ off2,
                       const float* __restrict__ W1l, const float* __restrict__ W1r,
                       ushort* __restrict__ wlt, ushort* __restrict__ wrt,
                       const float* __restrict__ W2l, const float* __restrict__ W2r,
                       float* __restrict__ w2lt, float* __restrict__ w2rt) {
    const int t = threadIdx.x;
    if (blockIdx.x >= 514) {  // W2 transpose (tiny)
        const int which = blockIdx.x - 514;
        const float* W = which ? W2r : W2l;
        float* Wt = which ? w2rt : w2lt;
        for (int idx = t; idx < kOUT * kHID; idx += 256) {
            const int tr = idx >> 8;       // 0..40
            const int k = idx & 255;
            Wt[idx] = W[(size_t)k * kOUT + tr];
        }
        return;
    }
    if (blockIdx.x >= 2) {  // W1 convert+transpose
        const int idx = blockIdx.x - 2;
        const int which = idx >> 8;
        const int j = idx & 255;
        const float* W = which ? W1r : W1l;
        ushort* Wt = which ? wrt : wlt;
        for (int k = t; k < kKP; k += 256) {
            float v = (k < kIN) ? W[(size_t)k * kHID + j] : 0.f;
            Wt[(size_t)j * kKP + k] = f2bf(v);
        }
        return;
    }
    __shared__ int part[256];
    const int* cnt = blockIdx.x ? cnt2 : cnt1;
    int* off = blockIdx.x ? off2 : off1;
    const int nN = blockIdx.x ? kN0 : kN1;
    const int CH = nN >> 8;
    const int base = t * CH;
    int s = 0;
    for (int i = 0; i < CH; ++i) s += cnt[base + i];
    part[t] = s;
    __syncthreads();
    for (int ofs = 1; ofs < 256; ofs <<= 1) {
        int v = (t >= ofs) ? part[t - ofs] : 0;
        __syncthreads();
        if (t >= ofs) part[t] += v;
        __syncthreads();
    }
    int run = (t == 0) ? 0 : part[t - 1];
    for (int i = 0; i < CH; ++i) {
        off[base + i] = run;
        run += cnt[base + i];
    }
    if (t == 255) off[nN] = run;
}

__global__ __launch_bounds__(256)
void bucket_both_kernel(const int* __restrict__ src1, const int* __restrict__ dst1,
                        const int* __restrict__ off1, int* __restrict__ cur1,
                        int* __restrict__ ebuf1,
                        const int* __restrict__ src2, const int* __restrict__ dst2,
                        const int* __restrict__ off2, int* __restrict__ cur2,
                        int* __restrict__ ebuf2) {
    const int gid = blockIdx.x * 256 + threadIdx.x;
    if (gid < kE1) {
        const int d = dst1[gid];
        const int p = atomicAdd(&cur1[d], 1);
        ebuf1[off1[d] + p] = src1[gid];
    } else if (gid < kE1 + kE2) {
        const int e = gid - kE1;
        const int d = dst2[e];
        const int p = atomicAdd(&cur2[d], 1);
        ebuf2[off2[d] + p] = src2[e];
    }
}

// ---------------------------------------------------------------------------
// Aggregation layer 1 + x[:N1] conversion fused (unchanged; measured at its
// delivered-bytes roofline ~6.2 TB/s mixed HBM+L3).
// ---------------------------------------------------------------------------
__global__ __launch_bounds__(128)
void aggregate1_kernel(const float* __restrict__ x, const int* __restrict__ off,
                       const int* __restrict__ ebuf, ushort* __restrict__ aggb,
                       ushort* __restrict__ xb) {
    const int d = blockIdx.x;
    const int t = threadIdx.x;
    const int b = off[d], e = off[d + 1];
    float p0x = 0.f, p0y = 0.f, p1x = 0.f, p1y = 0.f, p2x = 0.f, p2y = 0.f;
    float q0x = 0.f, q0y = 0.f, q1x = 0.f, q1y = 0.f, q2x = 0.f, q2y = 0.f;
    int i = b;
    for (; i + 4 <= e; i += 4) {
        const int s0 = ebuf[i], s1 = ebuf[i + 1];
        const int s2 = ebuf[i + 2], s3 = ebuf[i + 3];
        const float2* r0 = (const float2*)(x + (size_t)s0 * kIN);
        const float2* r1 = (const float2*)(x + (size_t)s1 * kIN);
        const float2* r2 = (const float2*)(x + (size_t)s2 * kIN);
        const float2* r3 = (const float2*)(x + (size_t)s3 * kIN);
        const float2 a0 = r0[t], a1 = r0[t + 128];
        const float2 b0 = r1[t], b1 = r1[t + 128];
        const float2 c0 = r2[t], c1 = r2[t + 128];
        const float2 d0 = r3[t], d1 = r3[t + 128];
        p0x += a0.x; p0y += a0.y; p1x += a1.x; p1y += a1.y;
        q0x += b0.x; q0y += b0.y; q1x += b1.x; q1y += b1.y;
        p0x += c0.x; p0y += c0.y; p1x += c1.x; p1y += c1.y;
        q0x += d0.x; q0y += d0.y; q1x += d1.x; q1y += d1.y;
        if (t < 45) {
            const float2 a2 = r0[t + 256], b2 = r1[t + 256];
            const float2 c2 = r2[t + 256], d2 = r3[t + 256];
            p2x += a2.x + c2.x; p2y += a2.y + c2.y;
            q2x += b2.x + d2.x; q2y += b2.y + d2.y;
        }
    }
    for (; i < e; ++i) {
        const int s0 = ebuf[i];
        const float2* r0 = (const float2*)(x + (size_t)s0 * kIN);
        const float2 a0 = r0[t], a1 = r0[t + 128];
        p0x += a0.x; p0y += a0.y; p1x += a1.x; p1y += a1.y;
        if (t < 45) {
            const float2 a2 = r0[t + 256];
            p2x += a2.x; p2y += a2.y;
        }
    }
    p0x += q0x; p0y += q0y; p1x += q1x; p1y += q1y; p2x += q2x; p2y += q2y;
    const float inv = 1.0f / fmaxf((float)(e - b), 1.0f);
    uint* ar = (uint*)(aggb + (size_t)d * kKP);
    ar[t]       = pack2(p0x * inv, p0y * inv);
    ar[t + 128] = pack2(p1x * inv, p1y * inv);
    if (t < 45) ar[t + 256] = pack2(p2x * inv, p2y * inv);
    if (t >= 45 && t < 48) ar[t + 256] = 0u;

    const float2* xr = (const float2*)(x + (size_t)d * kIN);
    uint* xo = (uint*)(xb + (size_t)d * kKP);
#pragma unroll
    for (int u = t; u < 304; u += 128) {
        uint v = 0u;
        if (u < 301) {
            const float2 f = xr[u];
            v = pack2(f.x, f.y);
        }
        xo[u] = v;
    }
}

// ---------------------------------------------------------------------------
// Layer-1 GEMM: BARRIER-FREE per-wave MFMA, DEPTH-3 pipeline, 32x256 blocks.
// h = relu(agg@W1l + b1 + x@W1r). Block = 32 rows x all 256 cols: 8 waves
// side-by-side (jbase = wid*32, each wave 32x32). Every A row is read by
// exactly ONE block -> A-pair HBM traffic halves vs R13 (110->55 MB); the 8
// waves share A rows through L1/L2 broadcast; B (0.6 MB) stays L2-resident.
// Grid 352 (= kN1/32) with bijective XCD chunk swizzle; 2816 waves, same
// VGPR/occupancy and same depth-3 named-set schedule as R13 (rule #20).
// ---------------------------------------------------------------------------
struct L1Frags {
    bf16x8 a[2];   // aggb rows m*16
    bf16x8 xx[2];  // xb rows
    bf16x8 wl[2];  // wlt rows n*16
    bf16x8 wr[2];  // wrt rows
};

__global__ __launch_bounds__(512)
void layer1_wave(const ushort* __restrict__ aggb, const ushort* __restrict__ xb,
                 const ushort* __restrict__ wlt, const ushort* __restrict__ wrt,
                 const float* __restrict__ b1, float* __restrict__ h) {
    const int t = threadIdx.x;
    const int lane = t & 63, wid = t >> 6;
    // XCD chunk swizzle: 352 blocks = 8 XCDs x 44 (bijective)
    const int bid = (int)(blockIdx.x & 7) * 44 + (int)(blockIdx.x >> 3);
    const int mrow = bid * 32;
    const int jbase = wid * 32;

    const int rl = lane & 15;
    const int k8 = lane >> 4;

    const ushort* pa0 = aggb + (size_t)(mrow + rl) * kKP + k8 * 8;
    const ushort* pa1 = pa0 + 16 * kKP;
    const ushort* px0 = xb + (size_t)(mrow + rl) * kKP + k8 * 8;
    const ushort* px1 = px0 + 16 * kKP;
    const ushort* pl0 = wlt + (size_t)(jbase + rl) * kKP + k8 * 8;
    const ushort* pl1 = pl0 + 16 * kKP;
    const ushort* pr0 = wrt + (size_t)(jbase + rl) * kKP + k8 * 8;
    const ushort* pr1 = pr0 + 16 * kKP;

    const int col_l = lane & 15;
    const float bias0 = b1[jbase + col_l];
    const float bias1 = b1[jbase + 16 + col_l];

    f32x4 acc[2][2];
#pragma unroll
    for (int m = 0; m < 2; ++m)
#pragma unroll
        for (int n = 0; n < 2; ++n) acc[m][n] = (f32x4){0.f, 0.f, 0.f, 0.f};

#define L1_LOAD(F, ks)                                               \
    do {                                                             \
        const int o = (ks) * 32;                                     \
        (F).a[0]  = *(const bf16x8*)(pa0 + o);                       \
        (F).a[1]  = *(const bf16x8*)(pa1 + o);                       \
        (F).xx[0] = *(const bf16x8*)(px0 + o);                       \
        (F).xx[1] = *(const bf16x8*)(px1 + o);                       \
        (F).wl[0] = *(const bf16x8*)(pl0 + o);                       \
        (F).wl[1] = *(const bf16x8*)(pl1 + o);                       \
        (F).wr[0] = *(const bf16x8*)(pr0 + o);                       \
        (F).wr[1] = *(const bf16x8*)(pr1 + o);                       \
    } while (0)

#define L1_MFMA(F)                                                   \
    do {                                                             \
        _Pragma("unroll") for (int m = 0; m < 2; ++m)                \
            _Pragma("unroll") for (int n = 0; n < 2; ++n) {          \
            acc[m][n] = __builtin_amdgcn_mfma_f32_16x16x32_bf16(     \
                (F).a[m], (F).wl[n], acc[m][n], 0, 0, 0);            \
            acc[m][n] = __builtin_amdgcn_mfma_f32_16x16x32_bf16(     \
                (F).xx[m], (F).wr[n], acc[m][n], 0, 0, 0);           \
        }                                                            \
    } while (0)

    L1Frags fr0, fr1, fr2;
    L1_LOAD(fr0, 0);
    L1_LOAD(fr1, 1);
    L1_LOAD(fr2, 2);
    L1_MFMA(fr0); L1_LOAD(fr0, 3);
    L1_MFMA(fr1); L1_LOAD(fr1, 4);
    L1_MFMA(fr2); L1_LOAD(fr2, 5);
    L1_MFMA(fr0); L1_LOAD(fr0, 6);
    L1_MFMA(fr1); L1_LOAD(fr1, 7);
    L1_MFMA(fr2); L1_LOAD(fr2, 8);
    L1_MFMA(fr0); L1_LOAD(fr0, 9);
    L1_MFMA(fr1); L1_LOAD(fr1, 10);
    L1_MFMA(fr2); L1_LOAD(fr2, 11);
    L1_MFMA(fr0); L1_LOAD(fr0, 12);
    L1_MFMA(fr1); L1_LOAD(fr1, 13);
    L1_MFMA(fr2); L1_LOAD(fr2, 14);
    L1_MFMA(fr0); L1_LOAD(fr0, 15);
    L1_MFMA(fr1); L1_LOAD(fr1, 16);
    L1_MFMA(fr2); L1_LOAD(fr2, 17);
    L1_MFMA(fr0); L1_LOAD(fr0, 18);
    L1_MFMA(fr1);  // ks = 16
    L1_MFMA(fr2);  // ks = 17
    L1_MFMA(fr0);  // ks = 18
#undef L1_LOAD
#undef L1_MFMA

    // C/D layout (validated R3-R13): col=lane&15, row=(lane>>4)*4+q
    const int rq = lane >> 4;
#pragma unroll
    for (int m = 0; m < 2; ++m)
#pragma unroll
        for (int n = 0; n < 2; ++n) {
            const int gc = jbase + n * 16 + col_l;
            const float bias = n ? bias1 : bias0;
#pragma unroll
            for (int q = 0; q < 4; ++q) {
                const int gr = mrow + m * 16 + rq * 4 + q;
                h[(size_t)gr * kHID + gc] = fmaxf(acc[m][n][q] + bias, 0.f);
            }
        }
}

// ---------------------------------------------------------------------------
// Layer 2 fused: gather-mean h[src2] rows (CSR, no atomics) + GEMV (with
// transposed W2: contiguous float4 per output col) + row log_softmax.
// ---------------------------------------------------------------------------
__global__ __launch_bounds__(64)
void layer2_fused(const float* __restrict__ h, const int* __restrict__ off,
                  const int* __restrict__ ebuf, const float* __restrict__ w2lt,
                  const float* __restrict__ w2rt, const float* __restrict__ b2,
                  float* __restrict__ out) {
    __shared__ float sa[kHID];
    __shared__ float sh[kHID];
    const int n = blockIdx.x;
    const int t = threadIdx.x;
    const int b = off[n], e = off[n + 1];
    float ax = 0.f, ay = 0.f, az = 0.f, aw = 0.f;
    for (int i = b; i < e; ++i) {
        const float4 r = ((const float4*)(h + (size_t)ebuf[i] * kHID))[t];
        ax += r.x; ay += r.y; az += r.z; aw += r.w;
    }
    const float inv = 1.0f / fmaxf((float)(e - b), 1.0f);
    float4 o;
    o.x = ax * inv; o.y = ay * inv; o.z = az * inv; o.w = aw * inv;
    ((float4*)sa)[t] = o;
    ((float4*)sh)[t] = ((const float4*)(h + (size_t)n * kHID))[t];
    __syncthreads();

    float logit = 0.0f;
    if (t < kOUT) {
        logit = b2[t];
        const float4* wl4 = (const float4*)(w2lt + (size_t)t * kHID);
        const float4* wr4 = (const float4*)(w2rt + (size_t)t * kHID);
        const float4* sa4 = (const float4*)sa;
        const float4* sh4 = (const float4*)sh;
#pragma unroll 8
        for (int k4 = 0; k4 < kHID / 4; ++k4) {
            const float4 a = sa4[k4], hh = sh4[k4];
            const float4 wl = wl4[k4], wr = wr4[k4];
            logit += a.x * wl.x + a.y * wl.y + a.z * wl.z + a.w * wl.w;
            logit += hh.x * wr.x + hh.y * wr.y + hh.z * wr.z + hh.w * wr.w;
        }
    }
    float m = (t < kOUT) ? logit : -INFINITY;
#pragma unroll
    for (int ofs = 32; ofs >= 1; ofs >>= 1)
        m = fmaxf(m, __shfl_xor(m, ofs));
    float ev = (t < kOUT) ? expf(logit - m) : 0.0f;
    float s = ev;
#pragma unroll
    for (int ofs = 32; ofs >= 1; ofs >>= 1)
        s += __shfl_xor(s, ofs);
    if (t < kOUT)
        out[(size_t)n * kOUT + t] = logit - m - logf(s);
}

// ---------------------------------------------------------------------------
extern "C" void kernel_launch(void* const* d_in, const int* in_sizes, int n_in,
                              void* d_out, int out_size, void* d_ws, size_t ws_size,
                              hipStream_t stream) {
    const float* x    = (const float*)d_in[0];
    const int*   src1 = (const int*)d_in[1];
    const int*   dst1 = (const int*)d_in[2];
    const int*   src2 = (const int*)d_in[3];
    const int*   dst2 = (const int*)d_in[4];
    const float* W1l  = (const float*)d_in[5];
    const float* W1r  = (const float*)d_in[6];
    const float* b1   = (const float*)d_in[7];
    const float* W2l  = (const float*)d_in[8];
    const float* W2r  = (const float*)d_in[9];
    const float* b2   = (const float*)d_in[10];
    float* out = (float*)d_out;

    // ---- workspace layout ----
    int* cnt1 = (int*)d_ws;                  // kN1
    int* cur1 = cnt1 + kN1;                  // kN1
    int* cnt2 = cur1 + kN1;                  // kN0
    int* cur2 = cnt2 + kN0;                  // kN0
    int* off1 = cur2 + kN0;                  // kN1 + 1
    int* off2 = off1 + kN1 + 1;              // kN0 + 1
    int* ebuf1 = off2 + kN0 + 1;             // kE1
    int* ebuf2 = ebuf1 + kE1;                // kE2
    size_t int_words = (size_t)2 * kN1 + 2 * kN0 + (kN1 + 1) + (kN0 + 1) + kE1 + kE2;
    int_words = (int_words + 7) & ~(size_t)7;  // 32B align

    ushort* aggb = (ushort*)((int*)d_ws + int_words);   // kN1*kKP bf16
    ushort* xb   = aggb + (size_t)kN1 * kKP;            // kN1*kKP
    ushort* wlt  = xb + (size_t)kN1 * kKP;              // kHID*kKP
    ushort* wrt  = wlt + (size_t)kHID * kKP;            // kHID*kKP
    float* w2lt  = (float*)(wrt + (size_t)kHID * kKP);  // kOUT*kHID fp32
    float* w2rt  = w2lt + (size_t)kOUT * kHID;          // kOUT*kHID fp32
    float* h     = w2rt + (size_t)kOUT * kHID;          // kN1*kHID fp32

    hipMemsetAsync(cnt1, 0, ((size_t)2 * kN1 + 2 * kN0) * sizeof(int), stream);

    constexpr int EB = (kE1 + kE2 + 255) / 256;  // 700
    hist_both_kernel<<<EB, 256, 0, stream>>>(dst1, dst2, cnt1, cnt2);
    scan_convw_kernel<<<516, 256, 0, stream>>>(cnt1, off1, cnt2, off2,
                                               W1l, W1r, wlt, wrt,
                                               W2l, W2r, w2lt, w2rt);
    bucket_both_kernel<<<EB, 256, 0, stream>>>(src1, dst1, off1, cur1, ebuf1,
                                               src2, dst2, off2, cur2, ebuf2);

    aggregate1_kernel<<<kN1, 128, 0, stream>>>(x, off1, ebuf1, aggb, xb);

    layer1_wave<<<352, 512, 0, stream>>>(aggb, xb, wlt, wrt, b1, h);

    layer2_fused<<<kN0, 64, 0, stream>>>(h, off2, ebuf2, w2lt, w2rt, b2, out);
}